// Round 1
// baseline (242.933 us; speedup 1.0000x reference)
//
#include <hip/hip_runtime.h>

typedef __bf16 bf16x8 __attribute__((ext_vector_type(8)));
typedef float f32x4 __attribute__((ext_vector_type(4)));
typedef unsigned short u16x8 __attribute__((ext_vector_type(8)));

#define S_LEN 2048
#define NHEAD 16
#define HDIM  64
#define EMB   1024

__device__ __forceinline__ ushort f2b(float v) {
  union { float f; unsigned u; } x; x.f = v;
  unsigned r = (x.u + 0x7fffu + ((x.u >> 16) & 1u)) >> 16;
  return (ushort)r;
}

__device__ __forceinline__ ushort f2b_trunc(float v) {
  union { float f; unsigned u; } x; x.f = v;
  return (ushort)(x.u >> 16);  // pattern-matches ds_write_b16_d16_hi
}

// async global->LDS, 16B per lane; LDS dest = wave-uniform base + lane*16
typedef const __attribute__((address_space(1))) unsigned int* gp1_t;
typedef __attribute__((address_space(3))) unsigned int* lp3_t;
__device__ __forceinline__ void gld16(const ushort* g, const ushort* l) {
  __builtin_amdgcn_global_load_lds((gp1_t)(unsigned long long)(uintptr_t)g,
                                   (lp3_t)(unsigned int)(uintptr_t)l, 16, 0, 0);
}

__device__ __forceinline__ void barf() {
  asm volatile("" ::: "memory");
  __builtin_amdgcn_s_barrier();
  asm volatile("" ::: "memory");
}

// ---------- fused prep: cast x -> bf16 (z==4) + transpose/cast weights (z<4) ----------
__global__ __launch_bounds__(256) void prep_kernel(
    const float* __restrict__ x, const float* __restrict__ W0,
    const float* __restrict__ W1, const float* __restrict__ W2,
    const float* __restrict__ W3, ushort* __restrict__ xb,
    ushort* __restrict__ Wt0, ushort* __restrict__ Wt1,
    ushort* __restrict__ Wt2, ushort* __restrict__ Wt3, float scale0) {
  const int z = blockIdx.z;
  if (z == 4) {  // x cast: 1024 blocks x 8192 floats
    size_t base = ((size_t)(blockIdx.y * 32 + blockIdx.x)) * 8192 + threadIdx.x * 4;
#pragma unroll
    for (int i = 0; i < 8; ++i) {
      float4 v = *(const float4*)(x + base + i * 1024);
      ushort4 o;
      o.x = f2b(v.x); o.y = f2b(v.y); o.z = f2b(v.z); o.w = f2b(v.w);
      *(ushort4*)(xb + base + i * 1024) = o;
    }
    return;
  }
  __shared__ float t[32][33];
  const float* W = z == 0 ? W0 : (z == 1 ? W1 : (z == 2 ? W2 : W3));
  ushort* Wt = z == 0 ? Wt0 : (z == 1 ? Wt1 : (z == 2 ? Wt2 : Wt3));
  const float scale = z == 0 ? scale0 : 1.0f;
  int k0 = blockIdx.x * 32, n0 = blockIdx.y * 32;
  int c = threadIdx.x & 31, r0 = threadIdx.x >> 5;
#pragma unroll
  for (int i = 0; i < 4; ++i) {
    int r = r0 + i * 8;
    t[r][c] = W[(size_t)(k0 + r) * EMB + n0 + c];
  }
  __syncthreads();
#pragma unroll
  for (int i = 0; i < 4; ++i) {
    int r = r0 + i * 8;
    Wt[(size_t)(n0 + r) * EMB + k0 + c] = f2b(t[c][r] * scale);
  }
}

// ---------------- GEMM v2: C[M,N] = A[M,K] * Bt[N,K]^T, bf16 MFMA ----------------
// 128x256 tile, BK=64, 8 waves (2M x 4N, per-wave 64x64), 512 threads.
// Counted-vmcnt pipeline (T3+T4) + setprio (T5): per K-tile 2 phases of
// 16 MFMA between raw s_barriers; staging pieces (A-kk half: 1 gld16,
// B-kk half: 2 gld16) issued 3-4 phases ahead into a 4-slot-per-matrix
// LDS ring ([kk][parity]); s_waitcnt vmcnt(3) once per K-tile (never 0
// mid-loop). LDS rows are 64B ([*][32 ushort]) -> minimal-conflict
// ds_read_b128 pattern, staged linearly (kk-split applied on the per-lane
// GLOBAL source address; LDS dest stays linear per rule #21).
// EPI==0: QKV epilogue (Q,K [b,h,s,d] bf16; V transposed [b,h,d,s]).
// EPI==1: fp32 out + bias.
template <int EPI>
__global__ __launch_bounds__(512, 2) void gemm8_kernel(
    const ushort* __restrict__ A, const ushort* __restrict__ Bt,
    ushort* __restrict__ outQ, ushort* __restrict__ outK, ushort* __restrict__ outVt,
    float* __restrict__ outF, const float* __restrict__ bias) {
  // A slots: 4 x [128][32] ushort at 0      (slot = (kk*2+par)*4096)
  // B slots: 4 x [256][32] ushort at 16384  (slot = (kk*2+par)*8192)
  __shared__ ushort lds8[49152];  // 96 KiB
  const int tid = threadIdx.x;
  const int wave = tid >> 6, lane = tid & 63, ln = lane & 15, quad = lane >> 4;
  const int wm = wave >> 2, wn = wave & 3;
  const long m0 = (long)blockIdx.x * 128, n0 = (long)blockIdx.y * 256;
  constexpr int K = EMB, KT = K / 64;  // 16 K-tiles

  // staging: per piece, thread covers bytes o = (ld*512+tid)*16 of the
  // [rows][32u] slot: row = o>>6, ushort col = (tid&3)*8
  const int srow = tid >> 2;
  const int scol = (tid & 3) * 8;
  const ushort* srcA  = A  + (m0 + srow) * (long)K + scol;         // + kk*32 + t*64
  const ushort* srcB0 = Bt + (n0 + srow) * (long)K + scol;
  const ushort* srcB1 = Bt + (n0 + 128 + srow) * (long)K + scol;
  const int dA_  = wave * 512;         // ushort offsets (wave-uniform)
  const int dB0_ = wave * 512;
  const int dB1_ = 4096 + wave * 512;

#define STG_A(kk, par, t)                                                      \
  gld16(srcA + (kk) * 32 + (t) * 64, lds8 + ((kk) * 2 + (par)) * 4096 + dA_)
#define STG_B(kk, par, t)                                                      \
  do {                                                                         \
    gld16(srcB0 + (kk) * 32 + (t) * 64,                                        \
          lds8 + 16384 + ((kk) * 2 + (par)) * 8192 + dB0_);                    \
    gld16(srcB1 + (kk) * 32 + (t) * 64,                                        \
          lds8 + 16384 + ((kk) * 2 + (par)) * 8192 + dB1_);                    \
  } while (0)

#define RD_A(kk, par)                                                          \
  do {                                                                         \
    const ushort* p_ = lds8 + ((kk) * 2 + (par)) * 4096 +                      \
                       (wm * 64 + ln) * 32 + quad * 8;                         \
    af[0] = *(const bf16x8*)p_;                                                \
    af[1] = *(const bf16x8*)(p_ + 512);                                        \
    af[2] = *(const bf16x8*)(p_ + 1024);                                       \
    af[3] = *(const bf16x8*)(p_ + 1536);                                       \
  } while (0)
#define RD_B(kk, par)                                                          \
  do {                                                                         \
    const ushort* p_ = lds8 + 16384 + ((kk) * 2 + (par)) * 8192 +              \
                       (wn * 64 + ln) * 32 + quad * 8;                         \
    bfr[0] = *(const bf16x8*)p_;                                               \
    bfr[1] = *(const bf16x8*)(p_ + 512);                                       \
    bfr[2] = *(const bf16x8*)(p_ + 1024);                                      \
    bfr[3] = *(const bf16x8*)(p_ + 1536);                                      \
  } while (0)

#define MM16()                                                                 \
  do {                                                                         \
    _Pragma("unroll") for (int mt = 0; mt < 4; ++mt)                           \
        _Pragma("unroll") for (int nt = 0; nt < 4; ++nt)                       \
            acc[mt][nt] = __builtin_amdgcn_mfma_f32_16x16x32_bf16(             \
                af[mt], bfr[nt], acc[mt][nt], 0, 0, 0);                        \
  } while (0)

  // ---- prologue: tile0 (both kk) + tile1 kk0; wait all-but-3, barrier ----
  STG_A(0, 0, 0); STG_B(0, 0, 0);
  STG_A(1, 0, 0); STG_B(1, 0, 0);
  STG_A(0, 1, 1); STG_B(0, 1, 1);
  asm volatile("s_waitcnt vmcnt(3)" ::: "memory");
  barf();

  f32x4 acc[4][4] = {};
  bf16x8 af[4], bfr[4];

  // ---- main loop: per K-tile 2 phases; stage kk1(t+1) at P0, kk0(t+2) at P1;
  //      boundary wait vmcnt(3) leaves tile-(t+2)-kk0 in flight. ----
#define TILE(t, par, parn)                                                     \
  do {                                                                         \
    /* P0: compute kk0 */                                                      \
    RD_A(0, par); RD_B(0, par);                                                \
    if ((t) + 1 < KT) { STG_A(1, parn, (t) + 1); STG_B(1, parn, (t) + 1); }    \
    barf();                                                                    \
    __builtin_amdgcn_s_setprio(1);                                             \
    MM16();                                                                    \
    __builtin_amdgcn_s_setprio(0);                                             \
    barf();                                                                    \
    /* P1: compute kk1 */                                                      \
    RD_A(1, par); RD_B(1, par);                                                \
    if ((t) + 2 < KT) { STG_A(0, par, (t) + 2); STG_B(0, par, (t) + 2); }      \
    barf();                                                                    \
    __builtin_amdgcn_s_setprio(1);                                             \
    MM16();                                                                    \
    __builtin_amdgcn_s_setprio(0);                                             \
    if ((t) + 2 < KT) {                                                        \
      asm volatile("s_waitcnt vmcnt(3)" ::: "memory");                         \
    } else if ((t) + 1 < KT) {                                                 \
      asm volatile("s_waitcnt vmcnt(0)" ::: "memory");                         \
    }                                                                          \
    barf();                                                                    \
  } while (0)

  for (int th = 0; th < KT; th += 2) {
    TILE(th, 0, 1);
    TILE(th + 1, 1, 0);
  }

  // ---- epilogue ----
  if (EPI == 0) {
    const int sel = (int)(n0 >> 10);  // block-uniform: 1024 | 256*4
    if (sel == 2) {
      // V: write transposed [bh][d][s]; 4 regs = 4 consecutive s -> uint2
#pragma unroll
      for (int mt = 0; mt < 4; ++mt) {
        const long mbase = m0 + wm * 64 + mt * 16 + quad * 4;
        const long bb = mbase >> 11, s = mbase & 2047;
#pragma unroll
        for (int nt = 0; nt < 4; ++nt) {
          const int nn = (int)((n0 & 1023) + wn * 64 + nt * 16 + ln);
          const int h = nn >> 6, d = nn & 63;
          uint2 val;
          val.x = (unsigned)f2b(acc[mt][nt][0]) | ((unsigned)f2b(acc[mt][nt][1]) << 16);
          val.y = (unsigned)f2b(acc[mt][nt][2]) | ((unsigned)f2b(acc[mt][nt][3]) << 16);
          *(uint2*)(outVt + (((bb * NHEAD + h) * (long)HDIM + d) * S_LEN) + s) = val;
        }
      }
    } else {
      ushort* dst = sel == 0 ? outQ : outK;
#pragma unroll
      for (int mt = 0; mt < 4; ++mt) {
#pragma unroll
        for (int nt = 0; nt < 4; ++nt) {
          const int nn = (int)((n0 & 1023) + wn * 64 + nt * 16 + ln);
          const int h = nn >> 6, d = nn & 63;
#pragma unroll
          for (int r = 0; r < 4; ++r) {
            const long m = m0 + wm * 64 + mt * 16 + quad * 4 + r;
            const long bb = m >> 11, s = m & 2047;
            dst[(((bb * NHEAD + h) * S_LEN) + s) * HDIM + d] = f2b(acc[mt][nt][r]);
          }
        }
      }
    }
  } else {
#pragma unroll
    for (int mt = 0; mt < 4; ++mt) {
#pragma unroll
      for (int nt = 0; nt < 4; ++nt) {
        const long n = n0 + wn * 64 + nt * 16 + ln;
        const float bv = bias[n];
#pragma unroll
        for (int r = 0; r < 4; ++r) {
          const long m = m0 + wm * 64 + mt * 16 + quad * 4 + r;
          outF[m * (long)EMB + n] = acc[mt][nt][r] + bv;
        }
      }
    }
  }
#undef TILE
#undef MM16
#undef RD_B
#undef RD_A
#undef STG_B
#undef STG_A
}

// ---------------- flash attention, v4 (unchanged) ----------------
// Q,K: [bh][s][d] bf16 (Q pre-scaled by log2e/8 via Wq).  Vt: [bh][d][s] bf16.
// Y: [b][s][h][d] bf16.
__global__ __launch_bounds__(256) void attn_kernel(const ushort* __restrict__ Q,
                                                   const ushort* __restrict__ Kg,
                                                   const ushort* __restrict__ Vt,
                                                   ushort* __restrict__ Y) {
  __shared__ alignas(16) ushort Ks[2][2 * 64 * 32];  // [buf][d-half][key][32]
  __shared__ alignas(16) ushort Vs[2][2 * 64 * 32];  // [buf][key-half][d][32]
  __shared__ alignas(16) ushort Ps[4 * 2 * 16 * 72]; // [wave][mt][16 rows][72]
  const int tid = threadIdx.x;
  const int wave = tid >> 6, lane = tid & 63, ln = lane & 15, quad = lane >> 4;
  const int bh = blockIdx.x;
  const int qb = 15 - (int)blockIdx.y;  // LPT: longest q-blocks first
  const int q0 = qb * 128;
  const size_t base = (size_t)bh * S_LEN * HDIM;
  const int ntiles = 2 * qb + 2;

  const u16x8 ob = {0x3F80, 0x3F80, 0x3F80, 0x3F80, 0x3F80, 0x3F80, 0x3F80, 0x3F80};
  const bf16x8 ones = __builtin_bit_cast(bf16x8, ob);

  bf16x8 qf[2][2];
#pragma unroll
  for (int mt = 0; mt < 2; ++mt)
#pragma unroll
    for (int ks2 = 0; ks2 < 2; ++ks2)
      qf[mt][ks2] = *(const bf16x8*)(Q + base + (size_t)(q0 + wave * 32 + mt * 16 + ln) * HDIM +
                                     ks2 * 32 + quad * 8);

  f32x4 acc[2][4] = {};
  f32x4 accl[2] = {};

  const int sr = lane >> 2, sc = (lane & 3) * 8;
  const ushort* KgL = Kg + base + (size_t)(16 * wave + sr) * HDIM + sc;
  const ushort* VgL = Vt + base + (size_t)(16 * wave + sr) * S_LEN + sc;

  {
    ushort* kb = &Ks[0][16 * wave * 32];
    ushort* vb = &Vs[0][16 * wave * 32];
    gld16(KgL, kb);
    gld16(KgL + 32, kb + 2048);
    gld16(VgL, vb);
    gld16(VgL + 32, vb + 2048);
  }
  __syncthreads();

  ushort* Pw0 = Ps + wave * 2304;
  ushort* Pw1 = Pw0 + 1152;
  const int swW = (quad >> 1) << 4;  // write-side swizzle: row = quad*4+r
  const int swR = (ln >> 3) << 4;    // read-side swizzle: row = ln

  for (int kt = 0; kt < ntiles; ++kt) {
    const int cur = kt & 1;
    const int k0 = kt * 64;
    if (kt + 1 < ntiles) {
      const int nb = cur ^ 1;
      const size_t k1 = (size_t)(k0 + 64);
      ushort* kb = &Ks[nb][16 * wave * 32];
      ushort* vb = &Vs[nb][16 * wave * 32];
      gld16(KgL + k1 * HDIM, kb);
      gld16(KgL + k1 * HDIM + 32, kb + 2048);
      gld16(VgL + k1, vb);
      gld16(VgL + k1 + 32, vb + 2048);
    }
    const ushort* Kc = &Ks[cur][0];
    const ushort* Vc = &Vs[cur][0];
    const int qbase = q0 + wave * 32;

    if (k0 < qbase + 32) {
      f32x4 s0[4] = {}, s1[4] = {};
#pragma unroll
      for (int ks2 = 0; ks2 < 2; ++ks2) {
#pragma unroll
        for (int nt = 0; nt < 4; ++nt) {
          bf16x8 bk = *(const bf16x8*)(Kc + ks2 * 2048 + (nt * 16 + ln) * 32 + quad * 8);
          s0[nt] = __builtin_amdgcn_mfma_f32_16x16x32_bf16(qf[0][ks2], bk, s0[nt], 0, 0, 0);
          s1[nt] = __builtin_amdgcn_mfma_f32_16x16x32_bf16(qf[1][ks2], bk, s1[nt], 0, 0, 0);
        }
      }

      if (k0 + 63 > qbase) {  // diagonal region: causal mask (also zeroes dead mt0)
        const int rowq = qbase + quad * 4;
#pragma unroll
        for (int nt = 0; nt < 4; ++nt)
#pragma unroll
          for (int r = 0; r < 4; ++r) {
            const int key = k0 + nt * 16 + ln;
            if (key > rowq + r) s0[nt][r] = -3.0e38f;
            if (key > rowq + 16 + r) s1[nt][r] = -3.0e38f;
          }
      }

      asm volatile("" ::: "memory");
#pragma unroll
      for (int nt = 0; nt < 4; ++nt) {
#pragma unroll
        for (int r = 0; r < 4; ++r) {
          float p0 = __builtin_amdgcn_exp2f(s0[nt][r]);
          float p1 = __builtin_amdgcn_exp2f(s1[nt][r]);
          const int row = (quad * 4 + r) * 72;
          const int col = (nt * 16 + ln) ^ swW;
          Pw0[row + col] = f2b_trunc(p0);
          Pw1[row + col] = f2b_trunc(p1);
        }
      }
      asm volatile("" ::: "memory");

#pragma unroll
      for (int ks2 = 0; ks2 < 2; ++ks2) {
        const int rcol = (ks2 * 32 + quad * 8) ^ swR;
        bf16x8 ap0 = *(const bf16x8*)(Pw0 + ln * 72 + rcol);
        bf16x8 ap1 = *(const bf16x8*)(Pw1 + ln * 72 + rcol);
        accl[0] = __builtin_amdgcn_mfma_f32_16x16x32_bf16(ap0, ones, accl[0], 0, 0, 0);
        accl[1] = __builtin_amdgcn_mfma_f32_16x16x32_bf16(ap1, ones, accl[1], 0, 0, 0);
#pragma unroll
        for (int t2 = 0; t2 < 4; ++t2) {
          bf16x8 bv = *(const bf16x8*)(Vc + ks2 * 2048 + (t2 * 16 + ln) * 32 + quad * 8);
          acc[0][t2] = __builtin_amdgcn_mfma_f32_16x16x32_bf16(ap0, bv, acc[0][t2], 0, 0, 0);
          acc[1][t2] = __builtin_amdgcn_mfma_f32_16x16x32_bf16(ap1, bv, acc[1][t2], 0, 0, 0);
        }
      }
    }
    __syncthreads();
  }

  const long b = bh >> 4;
  const int h = bh & 15;
#pragma unroll
  for (int mt = 0; mt < 2; ++mt) {
#pragma unroll
    for (int r = 0; r < 4; ++r) {
      float inv = 1.0f / accl[mt][r];
      const int qq = q0 + wave * 32 + mt * 16 + quad * 4 + r;
#pragma unroll
      for (int t2 = 0; t2 < 4; ++t2)
        Y[(((b * S_LEN + qq) * NHEAD) + h) * HDIM + t2 * 16 + ln] = f2b(acc[mt][t2][r] * inv);
    }
  }
}

extern "C" void kernel_launch(void* const* d_in, const int* in_sizes, int n_in,
                              void* d_out, int out_size, void* d_ws, size_t ws_size,
                              hipStream_t stream) {
  const float* x  = (const float*)d_in[0];
  const float* Wq = (const float*)d_in[1];
  const float* Wk = (const float*)d_in[2];
  const float* Wv = (const float*)d_in[3];
  const float* Wo = (const float*)d_in[4];
  const float* bo = (const float*)d_in[5];
  float* out = (float*)d_out;

  const size_t XE = (size_t)8192 * EMB;  // 8388608
  ushort* ws    = (ushort*)d_ws;
  ushort* xb    = ws;
  ushort* Wtqkv = xb + XE;
  ushort* Wto   = Wtqkv + 3 * 1048576;
  ushort* Qb    = Wto + 1048576;
  ushort* Kb    = Qb + XE;
  ushort* Vtb   = Kb + XE;
  ushort* Yb    = xb;  // alias: xb dead after QKV GEMM

  const float SCALE_Q = 1.4426950408889634f / 8.0f;  // log2(e)/sqrt(D)

  prep_kernel<<<dim3(32, 32, 5), 256, 0, stream>>>(
      x, Wq, Wk, Wv, Wo, xb, Wtqkv, Wtqkv + 1048576, Wtqkv + 2097152, Wto, SCALE_Q);

  // QKV: M=8192, N=3072 -> grid 64x12 = 768 blocks = exactly 3 CU-waves
  gemm8_kernel<0><<<dim3(64, 12), 512, 0, stream>>>(xb, Wtqkv, Qb, Kb, Vtb,
                                                    nullptr, nullptr);
  attn_kernel<<<dim3(64, 16), 256, 0, stream>>>(Qb, Kb, Vtb, Yb);
  // out-proj: M=8192, N=1024 -> grid 64x4 = 256 blocks = exactly 1 CU-wave
  gemm8_kernel<1><<<dim3(64, 4), 512, 0, stream>>>(Yb, Wto, nullptr, nullptr,
                                                   nullptr, out, bo);
}

// Round 2
// 230.557 us; speedup vs baseline: 1.0537x; 1.0537x over previous
//
#include <hip/hip_runtime.h>

typedef __bf16 bf16x8 __attribute__((ext_vector_type(8)));
typedef float f32x4 __attribute__((ext_vector_type(4)));
typedef unsigned short u16x8 __attribute__((ext_vector_type(8)));

#define S_LEN 2048
#define NHEAD 16
#define HDIM  64
#define EMB   1024

__device__ __forceinline__ ushort f2b(float v) {
  union { float f; unsigned u; } x; x.f = v;
  unsigned r = (x.u + 0x7fffu + ((x.u >> 16) & 1u)) >> 16;
  return (ushort)r;
}

__device__ __forceinline__ ushort f2b_trunc(float v) {
  union { float f; unsigned u; } x; x.f = v;
  return (ushort)(x.u >> 16);  // pattern-matches ds_write_b16_d16_hi
}

// async global->LDS, 16B per lane; LDS dest = wave-uniform base + lane*16
typedef const __attribute__((address_space(1))) unsigned int* gp1_t;
typedef __attribute__((address_space(3))) unsigned int* lp3_t;
__device__ __forceinline__ void gld16(const ushort* g, const ushort* l) {
  __builtin_amdgcn_global_load_lds((gp1_t)(unsigned long long)(uintptr_t)g,
                                   (lp3_t)(unsigned int)(uintptr_t)l, 16, 0, 0);
}

__device__ __forceinline__ void barf() {
  asm volatile("" ::: "memory");
  __builtin_amdgcn_s_barrier();
  asm volatile("" ::: "memory");
}

// ---------- fused prep: cast x -> bf16 (z==4) + transpose/cast weights (z<4) ----------
__global__ __launch_bounds__(256) void prep_kernel(
    const float* __restrict__ x, const float* __restrict__ W0,
    const float* __restrict__ W1, const float* __restrict__ W2,
    const float* __restrict__ W3, ushort* __restrict__ xb,
    ushort* __restrict__ Wt0, ushort* __restrict__ Wt1,
    ushort* __restrict__ Wt2, ushort* __restrict__ Wt3, float scale0) {
  const int z = blockIdx.z;
  if (z == 4) {  // x cast: 1024 blocks x 8192 floats
    size_t base = ((size_t)(blockIdx.y * 32 + blockIdx.x)) * 8192 + threadIdx.x * 4;
#pragma unroll
    for (int i = 0; i < 8; ++i) {
      float4 v = *(const float4*)(x + base + i * 1024);
      ushort4 o;
      o.x = f2b(v.x); o.y = f2b(v.y); o.z = f2b(v.z); o.w = f2b(v.w);
      *(ushort4*)(xb + base + i * 1024) = o;
    }
    return;
  }
  __shared__ float t[32][33];
  const float* W = z == 0 ? W0 : (z == 1 ? W1 : (z == 2 ? W2 : W3));
  ushort* Wt = z == 0 ? Wt0 : (z == 1 ? Wt1 : (z == 2 ? Wt2 : Wt3));
  const float scale = z == 0 ? scale0 : 1.0f;
  int k0 = blockIdx.x * 32, n0 = blockIdx.y * 32;
  int c = threadIdx.x & 31, r0 = threadIdx.x >> 5;
#pragma unroll
  for (int i = 0; i < 4; ++i) {
    int r = r0 + i * 8;
    t[r][c] = W[(size_t)(k0 + r) * EMB + n0 + c];
  }
  __syncthreads();
#pragma unroll
  for (int i = 0; i < 4; ++i) {
    int r = r0 + i * 8;
    Wt[(size_t)(n0 + r) * EMB + k0 + c] = f2b(t[c][r] * scale);
  }
}

// ---------------- GEMM v3: C[M,N] = A[M,K] * Bt[N,K]^T, bf16 MFMA ----------------
// 128x256 tile, BK=64, 8 waves (2M x 4N, per-wave 64x64), 512 threads.
// v3 change (T2): LDS tiles are [rows][64 ushort] (128B rows, full BK per row)
// with XOR swizzle slot16B ^= (row&7).  Read: lane(ln,quad) kk reads slot
// (kk*4+quad)^(ln&7) -> every consecutive-8-lane group covers all 8 slots
// exactly once => conflict-free ds_read_b128 (was 4-way, 6.29M conflict cyc).
// Write: global_load_lds dest stays LINEAR; the same involution is applied to
// the per-lane GLOBAL source column (rule #21: both-sides-or-neither).
// Pipeline: 3-slot ring (144KB), stage tile t+2 during t, s_waitcnt vmcnt(6)
// once per K-tile (counted, never 0 mid-loop), raw s_barrier, setprio on MFMA.
// EPI==0: QKV epilogue (Q,K [b,h,s,d] bf16; V transposed [b,h,d,s]).
// EPI==1: fp32 out + bias.
template <int EPI>
__global__ __launch_bounds__(512, 2) void gemm8_kernel(
    const ushort* __restrict__ A, const ushort* __restrict__ Bt,
    ushort* __restrict__ outQ, ushort* __restrict__ outK, ushort* __restrict__ outVt,
    float* __restrict__ outF, const float* __restrict__ bias) {
  // A slots: 3 x [128][64] ushort at 0      (slot s at s*8192 ushorts, 16KB)
  // B slots: 3 x [256][64] ushort at 24576  (slot s at 24576 + s*16384, 32KB)
  __shared__ ushort lds8[73728];  // 144 KiB
  const int tid = threadIdx.x;
  const int wave = tid >> 6, lane = tid & 63, ln = lane & 15, quad = lane >> 4;
  const int wm = wave >> 2, wn = wave & 3;
  const long m0 = (long)blockIdx.x * 128, n0 = (long)blockIdx.y * 256;
  constexpr int K = EMB, KT = K / 64;  // 16 K-tiles

  // ---- staging addresses (pre-swizzled global source, linear LDS dest) ----
  // 16B chunk j = ld*512 + tid of a slot: row = j>>3, slot16 c = j&7.
  // LDS(row, c) must hold data(row, c ^ (row&7)).  row&7 == (tid>>3)&7 for
  // all ld (ld steps rows by 64), so the per-thread source col is ld-invariant.
  const int srow = tid >> 3;                         // 0..63
  const int scol = ((tid & 7) ^ (srow & 7)) * 8;     // swizzled ushort col
  const ushort* srcA = A + (m0 + srow) * (long)K + scol;   // +t*64 +ld*64*K
  const ushort* srcB = Bt + (n0 + srow) * (long)K + scol;

#define STG_A(t, s)                                                            \
  do {                                                                         \
    gld16(srcA + (t) * 64,               lds8 + (s) * 8192 + tid * 8);         \
    gld16(srcA + (t) * 64 + 64 * K,      lds8 + (s) * 8192 + 4096 + tid * 8);  \
  } while (0)
#define STG_B(t, s)                                                            \
  do {                                                                         \
    gld16(srcB + (t) * 64,               lds8 + 24576 + (s) * 16384 + tid * 8);         \
    gld16(srcB + (t) * 64 + 64 * K,      lds8 + 24576 + (s) * 16384 + 4096 + tid * 8);  \
    gld16(srcB + (t) * 64 + 128 * K,     lds8 + 24576 + (s) * 16384 + 8192 + tid * 8);  \
    gld16(srcB + (t) * 64 + 192 * K,     lds8 + 24576 + (s) * 16384 + 12288 + tid * 8); \
  } while (0)

  // ---- fragment reads (swizzled col; row&7 == ln&7 since wm*64,mt*16 are 8-mult) ----
  const int sw = (ln & 7) * 8;

#define RD_A(kk, s)                                                            \
  do {                                                                         \
    const ushort* p_ = lds8 + (s) * 8192 + (wm * 64 + ln) * 64 +               \
                       (((kk) * 32 + quad * 8) ^ sw);                          \
    af[0] = *(const bf16x8*)p_;                                                \
    af[1] = *(const bf16x8*)(p_ + 1024);                                       \
    af[2] = *(const bf16x8*)(p_ + 2048);                                       \
    af[3] = *(const bf16x8*)(p_ + 3072);                                       \
  } while (0)
#define RD_B(kk, s)                                                            \
  do {                                                                         \
    const ushort* p_ = lds8 + 24576 + (s) * 16384 + (wn * 64 + ln) * 64 +      \
                       (((kk) * 32 + quad * 8) ^ sw);                          \
    bfr[0] = *(const bf16x8*)p_;                                               \
    bfr[1] = *(const bf16x8*)(p_ + 1024);                                      \
    bfr[2] = *(const bf16x8*)(p_ + 2048);                                      \
    bfr[3] = *(const bf16x8*)(p_ + 3072);                                      \
  } while (0)

#define MM16()                                                                 \
  do {                                                                         \
    _Pragma("unroll") for (int mt = 0; mt < 4; ++mt)                           \
        _Pragma("unroll") for (int nt = 0; nt < 4; ++nt)                       \
            acc[mt][nt] = __builtin_amdgcn_mfma_f32_16x16x32_bf16(             \
                af[mt], bfr[nt], acc[mt][nt], 0, 0, 0);                        \
  } while (0)

  // ---- prologue: stage tiles 0,1; wait tile0 (leave tile1's 6 in flight) ----
  STG_A(0, 0); STG_B(0, 0);
  STG_A(1, 1); STG_B(1, 1);
  asm volatile("s_waitcnt vmcnt(6)" ::: "memory");
  barf();

  f32x4 acc[4][4] = {};
  bf16x8 af[4], bfr[4];

  // ---- main loop: per tile 2 phases (kk0,kk1); stage A(t+2) in P0, B(t+2)
  //      in P1; boundary vmcnt(6) = t+1 landed, t+2's 6 still in flight. ----
#define TILE(t, s, sn)                                                         \
  do {                                                                         \
    RD_A(0, s); RD_B(0, s);                                                    \
    if ((t) + 2 < KT) STG_A((t) + 2, sn);                                      \
    barf();                                                                    \
    __builtin_amdgcn_s_setprio(1);                                             \
    MM16();                                                                    \
    __builtin_amdgcn_s_setprio(0);                                             \
    barf();                                                                    \
    RD_A(1, s); RD_B(1, s);                                                    \
    if ((t) + 2 < KT) STG_B((t) + 2, sn);                                      \
    barf();                                                                    \
    __builtin_amdgcn_s_setprio(1);                                             \
    MM16();                                                                    \
    __builtin_amdgcn_s_setprio(0);                                             \
    if ((t) + 2 < KT) {                                                        \
      asm volatile("s_waitcnt vmcnt(6)" ::: "memory");                         \
    } else if ((t) + 1 < KT) {                                                 \
      asm volatile("s_waitcnt vmcnt(0)" ::: "memory");                         \
    }                                                                          \
    barf();                                                                    \
  } while (0)

  // KT=16: 5 x 3 tiles + tail tile 15 (slot 15%3 == 0)
  for (int th = 0; th < 15; th += 3) {
    TILE(th, 0, 2);
    TILE(th + 1, 1, 0);
    TILE(th + 2, 2, 1);
  }
  TILE(15, 0, 2);

  // ---- epilogue ----
  if (EPI == 0) {
    const int sel = (int)(n0 >> 10);  // block-uniform: 1024 | 256*4
    if (sel == 2) {
      // V: write transposed [bh][d][s]; 4 regs = 4 consecutive s -> uint2
#pragma unroll
      for (int mt = 0; mt < 4; ++mt) {
        const long mbase = m0 + wm * 64 + mt * 16 + quad * 4;
        const long bb = mbase >> 11, s = mbase & 2047;
#pragma unroll
        for (int nt = 0; nt < 4; ++nt) {
          const int nn = (int)((n0 & 1023) + wn * 64 + nt * 16 + ln);
          const int h = nn >> 6, d = nn & 63;
          uint2 val;
          val.x = (unsigned)f2b(acc[mt][nt][0]) | ((unsigned)f2b(acc[mt][nt][1]) << 16);
          val.y = (unsigned)f2b(acc[mt][nt][2]) | ((unsigned)f2b(acc[mt][nt][3]) << 16);
          *(uint2*)(outVt + (((bb * NHEAD + h) * (long)HDIM + d) * S_LEN) + s) = val;
        }
      }
    } else {
      ushort* dst = sel == 0 ? outQ : outK;
#pragma unroll
      for (int mt = 0; mt < 4; ++mt) {
#pragma unroll
        for (int nt = 0; nt < 4; ++nt) {
          const int nn = (int)((n0 & 1023) + wn * 64 + nt * 16 + ln);
          const int h = nn >> 6, d = nn & 63;
#pragma unroll
          for (int r = 0; r < 4; ++r) {
            const long m = m0 + wm * 64 + mt * 16 + quad * 4 + r;
            const long bb = m >> 11, s = m & 2047;
            dst[(((bb * NHEAD + h) * S_LEN) + s) * HDIM + d] = f2b(acc[mt][nt][r]);
          }
        }
      }
    }
  } else {
#pragma unroll
    for (int mt = 0; mt < 4; ++mt) {
#pragma unroll
      for (int nt = 0; nt < 4; ++nt) {
        const long n = n0 + wn * 64 + nt * 16 + ln;
        const float bv = bias[n];
#pragma unroll
        for (int r = 0; r < 4; ++r) {
          const long m = m0 + wm * 64 + mt * 16 + quad * 4 + r;
          outF[m * (long)EMB + n] = acc[mt][nt][r] + bv;
        }
      }
    }
  }
#undef TILE
#undef MM16
#undef RD_B
#undef RD_A
#undef STG_B
#undef STG_A
}

// ---------------- flash attention, v4 (unchanged) ----------------
// Q,K: [bh][s][d] bf16 (Q pre-scaled by log2e/8 via Wq).  Vt: [bh][d][s] bf16.
// Y: [b][s][h][d] bf16.
__global__ __launch_bounds__(256) void attn_kernel(const ushort* __restrict__ Q,
                                                   const ushort* __restrict__ Kg,
                                                   const ushort* __restrict__ Vt,
                                                   ushort* __restrict__ Y) {
  __shared__ alignas(16) ushort Ks[2][2 * 64 * 32];  // [buf][d-half][key][32]
  __shared__ alignas(16) ushort Vs[2][2 * 64 * 32];  // [buf][key-half][d][32]
  __shared__ alignas(16) ushort Ps[4 * 2 * 16 * 72]; // [wave][mt][16 rows][72]
  const int tid = threadIdx.x;
  const int wave = tid >> 6, lane = tid & 63, ln = lane & 15, quad = lane >> 4;
  const int bh = blockIdx.x;
  const int qb = 15 - (int)blockIdx.y;  // LPT: longest q-blocks first
  const int q0 = qb * 128;
  const size_t base = (size_t)bh * S_LEN * HDIM;
  const int ntiles = 2 * qb + 2;

  const u16x8 ob = {0x3F80, 0x3F80, 0x3F80, 0x3F80, 0x3F80, 0x3F80, 0x3F80, 0x3F80};
  const bf16x8 ones = __builtin_bit_cast(bf16x8, ob);

  bf16x8 qf[2][2];
#pragma unroll
  for (int mt = 0; mt < 2; ++mt)
#pragma unroll
    for (int ks2 = 0; ks2 < 2; ++ks2)
      qf[mt][ks2] = *(const bf16x8*)(Q + base + (size_t)(q0 + wave * 32 + mt * 16 + ln) * HDIM +
                                     ks2 * 32 + quad * 8);

  f32x4 acc[2][4] = {};
  f32x4 accl[2] = {};

  const int sr = lane >> 2, sc = (lane & 3) * 8;
  const ushort* KgL = Kg + base + (size_t)(16 * wave + sr) * HDIM + sc;
  const ushort* VgL = Vt + base + (size_t)(16 * wave + sr) * S_LEN + sc;

  {
    ushort* kb = &Ks[0][16 * wave * 32];
    ushort* vb = &Vs[0][16 * wave * 32];
    gld16(KgL, kb);
    gld16(KgL + 32, kb + 2048);
    gld16(VgL, vb);
    gld16(VgL + 32, vb + 2048);
  }
  __syncthreads();

  ushort* Pw0 = Ps + wave * 2304;
  ushort* Pw1 = Pw0 + 1152;
  const int swW = (quad >> 1) << 4;  // write-side swizzle: row = quad*4+r
  const int swR = (ln >> 3) << 4;    // read-side swizzle: row = ln

  for (int kt = 0; kt < ntiles; ++kt) {
    const int cur = kt & 1;
    const int k0 = kt * 64;
    if (kt + 1 < ntiles) {
      const int nb = cur ^ 1;
      const size_t k1 = (size_t)(k0 + 64);
      ushort* kb = &Ks[nb][16 * wave * 32];
      ushort* vb = &Vs[nb][16 * wave * 32];
      gld16(KgL + k1 * HDIM, kb);
      gld16(KgL + k1 * HDIM + 32, kb + 2048);
      gld16(VgL + k1, vb);
      gld16(VgL + k1 + 32, vb + 2048);
    }
    const ushort* Kc = &Ks[cur][0];
    const ushort* Vc = &Vs[cur][0];
    const int qbase = q0 + wave * 32;

    if (k0 < qbase + 32) {
      f32x4 s0[4] = {}, s1[4] = {};
#pragma unroll
      for (int ks2 = 0; ks2 < 2; ++ks2) {
#pragma unroll
        for (int nt = 0; nt < 4; ++nt) {
          bf16x8 bk = *(const bf16x8*)(Kc + ks2 * 2048 + (nt * 16 + ln) * 32 + quad * 8);
          s0[nt] = __builtin_amdgcn_mfma_f32_16x16x32_bf16(qf[0][ks2], bk, s0[nt], 0, 0, 0);
          s1[nt] = __builtin_amdgcn_mfma_f32_16x16x32_bf16(qf[1][ks2], bk, s1[nt], 0, 0, 0);
        }
      }

      if (k0 + 63 > qbase) {  // diagonal region: causal mask (also zeroes dead mt0)
        const int rowq = qbase + quad * 4;
#pragma unroll
        for (int nt = 0; nt < 4; ++nt)
#pragma unroll
          for (int r = 0; r < 4; ++r) {
            const int key = k0 + nt * 16 + ln;
            if (key > rowq + r) s0[nt][r] = -3.0e38f;
            if (key > rowq + 16 + r) s1[nt][r] = -3.0e38f;
          }
      }

      asm volatile("" ::: "memory");
#pragma unroll
      for (int nt = 0; nt < 4; ++nt) {
#pragma unroll
        for (int r = 0; r < 4; ++r) {
          float p0 = __builtin_amdgcn_exp2f(s0[nt][r]);
          float p1 = __builtin_amdgcn_exp2f(s1[nt][r]);
          const int row = (quad * 4 + r) * 72;
          const int col = (nt * 16 + ln) ^ swW;
          Pw0[row + col] = f2b_trunc(p0);
          Pw1[row + col] = f2b_trunc(p1);
        }
      }
      asm volatile("" ::: "memory");

#pragma unroll
      for (int ks2 = 0; ks2 < 2; ++ks2) {
        const int rcol = (ks2 * 32 + quad * 8) ^ swR;
        bf16x8 ap0 = *(const bf16x8*)(Pw0 + ln * 72 + rcol);
        bf16x8 ap1 = *(const bf16x8*)(Pw1 + ln * 72 + rcol);
        accl[0] = __builtin_amdgcn_mfma_f32_16x16x32_bf16(ap0, ones, accl[0], 0, 0, 0);
        accl[1] = __builtin_amdgcn_mfma_f32_16x16x32_bf16(ap1, ones, accl[1], 0, 0, 0);
#pragma unroll
        for (int t2 = 0; t2 < 4; ++t2) {
          bf16x8 bv = *(const bf16x8*)(Vc + ks2 * 2048 + (t2 * 16 + ln) * 32 + quad * 8);
          acc[0][t2] = __builtin_amdgcn_mfma_f32_16x16x32_bf16(ap0, bv, acc[0][t2], 0, 0, 0);
          acc[1][t2] = __builtin_amdgcn_mfma_f32_16x16x32_bf16(ap1, bv, acc[1][t2], 0, 0, 0);
        }
      }
    }
    __syncthreads();
  }

  const long b = bh >> 4;
  const int h = bh & 15;
#pragma unroll
  for (int mt = 0; mt < 2; ++mt) {
#pragma unroll
    for (int r = 0; r < 4; ++r) {
      float inv = 1.0f / accl[mt][r];
      const int qq = q0 + wave * 32 + mt * 16 + quad * 4 + r;
#pragma unroll
      for (int t2 = 0; t2 < 4; ++t2)
        Y[(((b * S_LEN + qq) * NHEAD) + h) * HDIM + t2 * 16 + ln] = f2b(acc[mt][t2][r] * inv);
    }
  }
}

extern "C" void kernel_launch(void* const* d_in, const int* in_sizes, int n_in,
                              void* d_out, int out_size, void* d_ws, size_t ws_size,
                              hipStream_t stream) {
  const float* x  = (const float*)d_in[0];
  const float* Wq = (const float*)d_in[1];
  const float* Wk = (const float*)d_in[2];
  const float* Wv = (const float*)d_in[3];
  const float* Wo = (const float*)d_in[4];
  const float* bo = (const float*)d_in[5];
  float* out = (float*)d_out;

  const size_t XE = (size_t)8192 * EMB;  // 8388608
  ushort* ws    = (ushort*)d_ws;
  ushort* xb    = ws;
  ushort* Wtqkv = xb + XE;
  ushort* Wto   = Wtqkv + 3 * 1048576;
  ushort* Qb    = Wto + 1048576;
  ushort* Kb    = Qb + XE;
  ushort* Vtb   = Kb + XE;
  ushort* Yb    = xb;  // alias: xb dead after QKV GEMM

  const float SCALE_Q = 1.4426950408889634f / 8.0f;  // log2(e)/sqrt(D)

  prep_kernel<<<dim3(32, 32, 5), 256, 0, stream>>>(
      x, Wq, Wk, Wv, Wo, xb, Wtqkv, Wtqkv + 1048576, Wtqkv + 2097152, Wto, SCALE_Q);

  // QKV: M=8192, N=3072 -> grid 64x12 = 768 blocks = exactly 3 CU-waves
  gemm8_kernel<0><<<dim3(64, 12), 512, 0, stream>>>(xb, Wtqkv, Qb, Kb, Vtb,
                                                    nullptr, nullptr);
  attn_kernel<<<dim3(64, 16), 256, 0, stream>>>(Qb, Kb, Vtb, Yb);
  // out-proj: M=8192, N=1024 -> grid 64x4 = 256 blocks = exactly 1 CU-wave
  gemm8_kernel<1><<<dim3(64, 4), 512, 0, stream>>>(Yb, Wto, nullptr, nullptr,
                                                   nullptr, out, bo);
}